// Round 2
// baseline (192.709 us; speedup 1.0000x reference)
//
#include <hip/hip_runtime.h>
#include <hip/hip_bf16.h>

// y(x) = sum_{j=0..14} (b[j] < x) ? scale[j] : 0, accumulated in cumsum order.
// b[j] = cumsum(scale)[j] - scale[j]*0.5 (contraction OFF to match reference
// mul-then-sub rounding exactly -> no boundary-tie misclassification).

__device__ __forceinline__ float quant_one(float x, const float* __restrict__ s,
                                           const float* __restrict__ b) {
    float acc = 0.0f;
#pragma unroll
    for (int j = 0; j < 15; ++j) {
        acc += (b[j] < x) ? s[j] : 0.0f;   // exact: +0.0 on nonneg acc is identity
    }
    return acc;
}

__global__ __launch_bounds__(256) void nulsq_quant_kernel(
    const float* __restrict__ x, const float* __restrict__ scale,
    float* __restrict__ y, int n4, int n) {
#pragma clang fp contract(off)
    // Per-thread boundary/level computation: 15 broadcast loads (L1-cached),
    // sequential cumsum identical to jnp.cumsum order.
    float s[15], b[15];
    float c = 0.0f;
#pragma unroll
    for (int j = 0; j < 15; ++j) {
        s[j] = scale[j];
        c = c + s[j];                 // cumsum[j]
        b[j] = c - s[j] * 0.5f;       // boundary: mul then sub, no fma
    }

    const float4* __restrict__ x4 = reinterpret_cast<const float4*>(x);
    float4* __restrict__ y4 = reinterpret_cast<float4*>(y);

    int tid = blockIdx.x * blockDim.x + threadIdx.x;
    int stride = gridDim.x * blockDim.x;

    for (int i = tid; i < n4; i += stride) {
        float4 v = x4[i];
        float4 r;
        r.x = quant_one(v.x, s, b);
        r.y = quant_one(v.y, s, b);
        r.z = quant_one(v.z, s, b);
        r.w = quant_one(v.w, s, b);
        y4[i] = r;
    }

    // Scalar tail (n not divisible by 4 — not hit for this shape, kept for safety).
    for (int i = n4 * 4 + tid; i < n; i += stride) {
        y[i] = quant_one(x[i], s, b);
    }
}

extern "C" void kernel_launch(void* const* d_in, const int* in_sizes, int n_in,
                              void* d_out, int out_size, void* d_ws, size_t ws_size,
                              hipStream_t stream) {
    const float* x = (const float*)d_in[0];
    const float* scale = (const float*)d_in[1];
    float* y = (float*)d_out;

    int n = in_sizes[0];
    int n4 = n / 4;

    const int block = 256;
    int grid = (n4 + block - 1) / block;
    if (grid > 2048) grid = 2048;      // 8 blocks/CU * 256 CU; grid-stride the rest
    if (grid < 1) grid = 1;

    nulsq_quant_kernel<<<grid, block, 0, stream>>>(x, scale, y, n4, n);
}

// Round 6
// 189.429 us; speedup vs baseline: 1.0173x; 1.0173x over previous
//
#include <hip/hip_runtime.h>
#include <hip/hip_bf16.h>

// y(x) = sum_{j=0..14} (b[j] < x) ? scale[j] : 0, accumulated in cumsum order
// (exact vs reference: partial sums ARE the cumsum levels; +0.0 on nonneg acc
// is identity). b[j] = cumsum[j] - scale[j]*0.5 with contraction OFF to match
// the reference's mul-then-sub rounding at bucket boundaries.
//
// Latency-bound fix (round 3/4): 4 float4 per thread, all 4 loads issued
// before any compute (4x memory-level parallelism per wave), exact grid
// (6272 blocks * 256 thr * 4 f4 = 25690112 elements, zero tail this shape),
// nontemporal stores for the write-once output. Round 4: use clang native
// ext_vector float4 (HIP_vector_type is rejected by the nontemporal builtin).

typedef float vfloat4 __attribute__((ext_vector_type(4)));

__device__ __forceinline__ float quant_one(float x, const float* __restrict__ s,
                                           const float* __restrict__ b) {
    float acc = 0.0f;
#pragma unroll
    for (int j = 0; j < 15; ++j) {
        acc += (b[j] < x) ? s[j] : 0.0f;
    }
    return acc;
}

__global__ __launch_bounds__(256) void nulsq_quant_kernel(
    const float* __restrict__ x, const float* __restrict__ scale,
    float* __restrict__ y, int n4, int n) {
#pragma clang fp contract(off)
    float s[15], b[15];
    float c = 0.0f;
#pragma unroll
    for (int j = 0; j < 15; ++j) {
        s[j] = scale[j];            // broadcast loads, L1-cached
        c = c + s[j];               // cumsum[j]
        b[j] = c - s[j] * 0.5f;     // boundary: mul then sub, no fma
    }

    const vfloat4* __restrict__ x4 = reinterpret_cast<const vfloat4*>(x);
    vfloat4* __restrict__ y4 = reinterpret_cast<vfloat4*>(y);

    // Each thread owns 4 float4 chunks at stride 256 within its block's
    // 1024-f4 slab: coalesced within the wave, independent loads.
    const int base = blockIdx.x * 1024 + (int)threadIdx.x;

    vfloat4 v[4];
    bool ok[4];
    int fi[4];
#pragma unroll
    for (int k = 0; k < 4; ++k) {
        fi[k] = base + k * 256;
        ok[k] = fi[k] < n4;
        if (ok[k]) v[k] = x4[fi[k]];   // 4 loads in flight before any compute
    }

#pragma unroll
    for (int k = 0; k < 4; ++k) {
        if (ok[k]) {
            vfloat4 r;
            r.x = quant_one(v[k].x, s, b);
            r.y = quant_one(v[k].y, s, b);
            r.z = quant_one(v[k].z, s, b);
            r.w = quant_one(v[k].w, s, b);
            __builtin_nontemporal_store(r, &y4[fi[k]]);
        }
    }

    // Scalar tail for n % 4 != 0 (not hit for this shape): first few threads
    // of block 0 cover it.
    if (blockIdx.x == 0) {
        int tail = n - n4 * 4;
        if ((int)threadIdx.x < tail) {
            int i = n4 * 4 + (int)threadIdx.x;
            y[i] = quant_one(x[i], s, b);
        }
    }
}

extern "C" void kernel_launch(void* const* d_in, const int* in_sizes, int n_in,
                              void* d_out, int out_size, void* d_ws, size_t ws_size,
                              hipStream_t stream) {
    const float* x = (const float*)d_in[0];
    const float* scale = (const float*)d_in[1];
    float* y = (float*)d_out;

    int n = in_sizes[0];
    int n4 = n / 4;

    const int block = 256;
    const int f4_per_block = block * 4;                 // 1024
    int grid = (n4 + f4_per_block - 1) / f4_per_block;  // 6272 for this shape
    if (grid < 1) grid = 1;

    nulsq_quant_kernel<<<grid, block, 0, stream>>>(x, scale, y, n4, n);
}